// Round 1
// 33132.712 us; speedup vs baseline: 1.9312x; 1.9312x over previous
//
#include <hip/hip_runtime.h>
#include <hip/hip_bf16.h>

#define NB 4096
#define MDIM 327
#define NDIM 800
#define NLAYERS 9
#define NPIX 800
#define CHN 32
#define NBP (NB * NPIX)

typedef __hip_bfloat16 bf16;

// ---------------- setup ----------------

__global__ void k_copy(const float* __restrict__ src, float* __restrict__ dst,
                       long long n) {
    long long i0 = (long long)blockIdx.x * 256 + threadIdx.x;
    long long stride = (long long)gridDim.x * 256;
    for (long long i = i0; i < n; i += stride) dst[i] = src[i];
}

// transpose [O=32][I*9=288] -> [288][32]
__global__ void k_wtrans(const float* __restrict__ src, float* __restrict__ dst) {
    int idx = blockIdx.x * 256 + threadIdx.x;
    if (idx >= 9216) return;
    int o = idx / 288, r = idx % 288;
    dst[r * 32 + o] = src[idx];
}

__global__ void k_phitphi(const float* __restrict__ W, float* __restrict__ P) {
    int b = blockIdx.x * 16 + threadIdx.x;
    int a = blockIdx.y * 16 + threadIdx.y;
    float acc = 0.f;
    for (int k = 0; k < MDIM; ++k)
        acc += W[k * NDIM + a] * W[k * NDIM + b];
    P[(size_t)a * NDIM + b] = acc;
}

__global__ void k_wloss(const float* __restrict__ W, float* __restrict__ out) {
    int idx = blockIdx.x * 256 + threadIdx.x;
    if (idx >= MDIM * MDIM) return;
    int a = idx / MDIM, b = idx % MDIM;
    float acc = 0.f;
    for (int n = 0; n < NDIM; ++n)
        acc += W[a * NDIM + n] * W[b * NDIM + n];
    if (a == b) acc -= 1.f;
    out[idx] = acc;
}

__global__ void k_phitb(const float* __restrict__ y, const float* __restrict__ W,
                        float* __restrict__ PB) {
    int idx = blockIdx.x * 256 + threadIdx.x;
    if (idx >= NBP) return;
    int b = idx / NDIM, n = idx % NDIM;
    float acc = 0.f;
    for (int k = 0; k < MDIM; ++k)
        acc += y[b * MDIM + k] * W[k * NDIM + n];
    PB[idx] = acc;
}

// ---------------- X update ----------------

__global__ void k_x0(const float* __restrict__ PB, float* __restrict__ X1,
                     const float* __restrict__ hv) {
    int idx = blockIdx.x * 256 + threadIdx.x;
    if (idx >= NBP) return;
    X1[idx] = hv[0] * PB[idx];
}

// H = hatx = (1+tx)*Xc - tx*Xp
__global__ void k_hatx(const float* __restrict__ Xc, const float* __restrict__ Xp,
                       float* __restrict__ H, const float* __restrict__ txv,
                       int layer, int mode) {
    int idx = blockIdx.x * 256 + threadIdx.x;
    if (idx >= NBP) return;
    float tx = txv[layer];
    float xc = Xc[idx];
    float xp = (mode >= 2) ? Xp[idx] : 0.f;
    H[idx] = (1.f + tx) * xc - tx * xp;
}

// Xn = H*(1-h*b1) + h*PB - h*(H@P) + h*b1*Z - h*L
__global__ void k_xmm(const float* __restrict__ H, const float* __restrict__ P,
                      const float* __restrict__ PB, const float* __restrict__ Lc,
                      const float* __restrict__ Zc, float* __restrict__ Xn,
                      const float* __restrict__ hv, const float* __restrict__ b1v,
                      int layer, int mode) {
    __shared__ float As[64][17];
    __shared__ float Bs[16][65];
    int tid = threadIdx.x;
    float h = hv[layer], b1 = b1v[layer];
    int rowbase = blockIdx.y * 64, colbase = blockIdx.x * 64;
    int ttx = tid % 16, tty = tid / 16;
    float acc[4][4];
#pragma unroll
    for (int r = 0; r < 4; ++r)
#pragma unroll
        for (int c = 0; c < 4; ++c) acc[r][c] = 0.f;

    int am = tid >> 2, ak4 = (tid & 3) * 4;
    int bk = tid >> 4, bn4 = (tid & 15) * 4;

    for (int kt = 0; kt < 50; ++kt) {
        int k0 = kt * 16;
        {
            const float* hp = H + (size_t)(rowbase + am) * NDIM + k0 + ak4;
#pragma unroll
            for (int j = 0; j < 4; ++j) As[am][ak4 + j] = hp[j];
        }
        {
            const float* pr = P + (size_t)(k0 + bk) * NDIM + colbase + bn4;
#pragma unroll
            for (int j = 0; j < 4; ++j) {
                int col = colbase + bn4 + j;
                Bs[bk][bn4 + j] = (col < NDIM) ? pr[j] : 0.f;
            }
        }
        __syncthreads();
#pragma unroll
        for (int kk = 0; kk < 16; ++kk) {
            float a[4], b[4];
#pragma unroll
            for (int r = 0; r < 4; ++r) a[r] = As[tty * 4 + r][kk];
#pragma unroll
            for (int c = 0; c < 4; ++c) b[c] = Bs[kk][ttx * 4 + c];
#pragma unroll
            for (int r = 0; r < 4; ++r)
#pragma unroll
                for (int c = 0; c < 4; ++c) acc[r][c] += a[r] * b[c];
        }
        __syncthreads();
    }

#pragma unroll
    for (int r = 0; r < 4; ++r) {
        int row = rowbase + tty * 4 + r;
#pragma unroll
        for (int c = 0; c < 4; ++c) {
            int col = colbase + ttx * 4 + c;
            if (col >= NDIM) continue;
            size_t idx = (size_t)row * NDIM + col;
            float hx = H[idx];
            float zt = (mode == 2) ? Zc[idx] : 0.f;
            float lt = (mode == 2) ? Lc[idx] : 0.f;
            Xn[idx] = hx * (1.f - h * b1) + h * PB[idx] - h * acc[r][c] + h * b1 * zt - h * lt;
        }
    }
}

// ---------------- z_flat ----------------

__global__ void k_zflat(const float* __restrict__ Xn, const float* __restrict__ Zc,
                        const float* __restrict__ Zp, const float* __restrict__ Lc,
                        float* __restrict__ zf,
                        const float* __restrict__ hv, const float* __restrict__ b2v,
                        const float* __restrict__ tzv, int layer, int mode) {
    int idx = blockIdx.x * 256 + threadIdx.x;
    if (idx >= NBP) return;
    float h = hv[layer], b2 = b2v[layer], tz = tzv[layer];
    float hatz, lt;
    if (mode == 0) { hatz = 0.f; lt = 0.f; }
    else if (mode == 1) { hatz = (1.f + tz) * Zc[idx]; lt = 0.f; }
    else {
        float zc = Zc[idx], zp = Zp[idx];
        hatz = zc + tz * (zc - zp);
        lt = Lc[idx];
    }
    zf[idx] = hatz + h * (lt + b2 * (Xn[idx] - hatz));
}

// ---------------- convs (f32) ----------------
// All conv kernels: 512 threads = 8 waves, 2 blocks/CU (LDS-limited).
// Padded-LDS layout: rows of 42 floats (zero border cols), 12 rows per half
// (1 halo row each side) -> NO boundary conditionals in inner loops.
// Wave-uniform weight addressing via readfirstlane -> scalar (SMEM) loads.
// Lane map within a wave: lane < 50 active; ry = lane/5 (output row 0..9
// of the half), xg = (lane%5)*8 (8-pixel group). Each lane produces
// 4 output channels x 8 pixels.

// 1->32 conv + relu. w: [32][1][3][3] raw.
__global__ void __launch_bounds__(512, 4)
k_conv1f(const float* __restrict__ zf, float* __restrict__ out,
         const float* __restrict__ w, int c0) {
    __shared__ float zs[22 * 42];
    int tid = threadIdx.x;
    int img = c0 + blockIdx.x;
    for (int i = tid; i < 22 * 42; i += 512) zs[i] = 0.f;
    __syncthreads();
    for (int p = tid; p < NPIX; p += 512) {
        int y = p / 40, x = p % 40;
        zs[(y + 1) * 42 + (x + 1)] = zf[(size_t)img * NPIX + p];
    }
    __syncthreads();

    int wv = __builtin_amdgcn_readfirstlane(tid >> 6);
    int ob = wv * 4;
    int lane = tid & 63;
    int ry = lane / 5;
    int xg = (lane % 5) * 8;
    bool active = lane < 50;

    float wreg[4][9];
#pragma unroll
    for (int oo = 0; oo < 4; ++oo)
#pragma unroll
        for (int q = 0; q < 9; ++q) wreg[oo][q] = w[(ob + oo) * 9 + q];

    if (active) {
#pragma unroll
        for (int half = 0; half < 2; ++half) {
            int orow = half * 10 + ry;
            float pv[3][10];
#pragma unroll
            for (int r = 0; r < 3; ++r)
#pragma unroll
                for (int j = 0; j < 10; ++j)
                    pv[r][j] = zs[(orow + r) * 42 + xg + j];
            float acc[4][8];
#pragma unroll
            for (int oo = 0; oo < 4; ++oo)
#pragma unroll
                for (int j = 0; j < 8; ++j) acc[oo][j] = 0.f;
#pragma unroll
            for (int ky = 0; ky < 3; ++ky)
#pragma unroll
                for (int kx = 0; kx < 3; ++kx) {
                    int q = ky * 3 + kx;
#pragma unroll
                    for (int j = 0; j < 8; ++j) {
                        float p = pv[ky][kx + j];
                        acc[0][j] += wreg[0][q] * p;
                        acc[1][j] += wreg[1][q] * p;
                        acc[2][j] += wreg[2][q] * p;
                        acc[3][j] += wreg[3][q] * p;
                    }
                }
#pragma unroll
            for (int oo = 0; oo < 4; ++oo) {
                float* op = out + (size_t)blockIdx.x * 25600 + (ob + oo) * 800
                            + orow * 40 + xg;
#pragma unroll
                for (int j = 0; j < 8; ++j) op[j] = fmaxf(acc[oo][j], 0.f);
            }
        }
    }
}

// 32->32 conv. wT: [ci*9+ky*3+kx][32 o]. Optional soft-threshold on input,
// relu on output.
__global__ void __launch_bounds__(512, 4)
k_conv32(const float* __restrict__ in, float* __restrict__ out,
         const float* __restrict__ wT, const float* __restrict__ thrv,
         int layer, int softflag, int reluflag) {
    __shared__ float inS[CHN * 12 * 42];   // 64512 B
    int tid = threadIdx.x;
    const float* ip = in + (size_t)blockIdx.x * 25600;
    float thr = softflag ? fabsf(thrv[layer]) : 0.f;

    int wv = __builtin_amdgcn_readfirstlane(tid >> 6);
    int ob = wv * 4;
    int lane = tid & 63;
    int ry = lane / 5;
    int xg = (lane % 5) * 8;
    bool active = lane < 50;

    for (int half = 0; half < 2; ++half) {
        int r0 = half * 10 - 1;
        // stage padded: rows r0..r0+11, cols -1..40 (zero outside)
        for (int idx = tid; idx < CHN * 12 * 42; idx += 512) {
            int c = idx / 504;
            int rem = idx - c * 504;
            int rr = rem / 42;
            int cc = rem - rr * 42;
            int gr = r0 + rr, gx = cc - 1;
            float v = 0.f;
            if (gr >= 0 && gr < 20 && gx >= 0 && gx < 40) {
                v = ip[c * 800 + gr * 40 + gx];
                if (softflag) {
                    float a = fabsf(v) - thr;
                    v = (a > 0.f) ? copysignf(a, v) : 0.f;
                }
            }
            inS[idx] = v;
        }
        __syncthreads();

        if (active) {
            float acc[4][8];
#pragma unroll
            for (int oo = 0; oo < 4; ++oo)
#pragma unroll
                for (int j = 0; j < 8; ++j) acc[oo][j] = 0.f;

            const float* wbase = wT + ob;
#pragma unroll 1
            for (int ci = 0; ci < CHN; ++ci) {
                const float* rs = inS + ci * 504 + ry * 42 + xg;
                float pv[3][10];
#pragma unroll
                for (int r = 0; r < 3; ++r)
#pragma unroll
                    for (int j = 0; j < 10; ++j) pv[r][j] = rs[r * 42 + j];
                const float* wc = wbase + ci * 288;   // 9 quads, stride 32
#pragma unroll
                for (int ky = 0; ky < 3; ++ky)
#pragma unroll
                    for (int kx = 0; kx < 3; ++kx) {
                        int q = ky * 3 + kx;
                        float w0 = wc[q * 32 + 0];
                        float w1 = wc[q * 32 + 1];
                        float w2 = wc[q * 32 + 2];
                        float w3 = wc[q * 32 + 3];
#pragma unroll
                        for (int j = 0; j < 8; ++j) {
                            float p = pv[ky][kx + j];
                            acc[0][j] += w0 * p;
                            acc[1][j] += w1 * p;
                            acc[2][j] += w2 * p;
                            acc[3][j] += w3 * p;
                        }
                    }
            }

            int orow = half * 10 + ry;
#pragma unroll
            for (int oo = 0; oo < 4; ++oo) {
                float* op = out + (size_t)blockIdx.x * 25600 + (ob + oo) * 800
                            + orow * 40 + xg;
#pragma unroll
                for (int j = 0; j < 8; ++j) {
                    float v = acc[oo][j];
                    if (reluflag) v = fmaxf(v, 0.f);
                    op[j] = v;
                }
            }
        }
        __syncthreads();
    }
}

// 32->1 conv; writes f32 to global output; optional -z_in.
// 8 waves each own 4 input channels; partial sums reduced through LDS
// (aliased onto the staging buffer to stay under the 64KB static limit).
__global__ void __launch_bounds__(512, 4)
k_conv2b(const float* __restrict__ in, const float* __restrict__ w,
         const float* __restrict__ zf, float* __restrict__ out,
         int subz, int c0) {
    __shared__ float inS[CHN * 12 * 42];   // 64512 B; first 3200 reused as psum
    float* psum = inS;
    int tid = threadIdx.x;
    int img = c0 + blockIdx.x;
    const float* ip = in + (size_t)blockIdx.x * 25600;

    int wv = __builtin_amdgcn_readfirstlane(tid >> 6);
    int cibase = wv * 4;
    int lane = tid & 63;
    int ry = lane / 5;
    int xg = (lane % 5) * 8;
    bool active = lane < 50;

    for (int half = 0; half < 2; ++half) {
        int r0 = half * 10 - 1;
        for (int idx = tid; idx < CHN * 12 * 42; idx += 512) {
            int c = idx / 504;
            int rem = idx - c * 504;
            int rr = rem / 42;
            int cc = rem - rr * 42;
            int gr = r0 + rr, gx = cc - 1;
            inS[idx] = (gr >= 0 && gr < 20 && gx >= 0 && gx < 40)
                           ? ip[c * 800 + gr * 40 + gx] : 0.f;
        }
        __syncthreads();

        float acc[8];
#pragma unroll
        for (int j = 0; j < 8; ++j) acc[j] = 0.f;
        if (active) {
#pragma unroll
            for (int k = 0; k < 4; ++k) {
                int ci = cibase + k;
                const float* rs = inS + ci * 504 + ry * 42 + xg;
                float pv[3][10];
#pragma unroll
                for (int r = 0; r < 3; ++r)
#pragma unroll
                    for (int j = 0; j < 10; ++j) pv[r][j] = rs[r * 42 + j];
                const float* wc = w + ci * 9;
#pragma unroll
                for (int ky = 0; ky < 3; ++ky)
#pragma unroll
                    for (int kx = 0; kx < 3; ++kx) {
                        float wq = wc[ky * 3 + kx];
#pragma unroll
                        for (int j = 0; j < 8; ++j)
                            acc[j] += wq * pv[ky][kx + j];
                    }
            }
        }
        __syncthreads();   // everyone done READING inS before aliasing as psum
        if (active) {
#pragma unroll
            for (int j = 0; j < 8; ++j)
                psum[wv * 400 + ry * 40 + xg + j] = acc[j];
        }
        __syncthreads();
        for (int p = tid; p < 400; p += 512) {
            float s = 0.f;
#pragma unroll
            for (int u = 0; u < 8; ++u) s += psum[u * 400 + p];
            size_t gidx = (size_t)img * NPIX + half * 400 + p;
            if (subz) s -= zf[gidx];
            out[gidx] = s;
        }
        __syncthreads();
    }
}

// ---------------- L update ----------------

__global__ void k_lup(const float* __restrict__ Xn, const float* __restrict__ Zn,
                      const float* __restrict__ Lc, const float* __restrict__ Lp,
                      float* __restrict__ Ln,
                      const float* __restrict__ hv, const float* __restrict__ b1v,
                      const float* __restrict__ tLv, int layer, int mode) {
    int idx = blockIdx.x * 256 + threadIdx.x;
    if (idx >= NBP) return;
    float h = hv[layer], b1 = b1v[layer], tL = tLv[layer];
    float hatL;
    if (mode == 0) hatL = 0.f;
    else if (mode == 1) hatL = (1.f + tL) * Lc[idx];
    else {
        float lc = Lc[idx], lp = Lp[idx];
        hatL = lc + tL * (lc - lp);
    }
    Ln[idx] = hatL + h * b1 * (Xn[idx] - Zn[idx]);
}

// ---------------- host ----------------
// PROBE-VERIFIED (round 5): inputs f32, dict order, n_in=14, output f32, ws>=120MB.

extern "C" void kernel_launch(void* const* d_in, const int* in_sizes, int n_in,
                              void* d_out, int out_size, void* d_ws, size_t ws_size,
                              hipStream_t stream) {
    const float* y    = (const float*)d_in[0];
    const float* Wf   = (const float*)d_in[2];
    const float* b1v  = (const float*)d_in[3];
    const float* b2v  = (const float*)d_in[4];
    const float* hv   = (const float*)d_in[5];
    const float* stv  = (const float*)d_in[6];
    const float* txv  = (const float*)d_in[7];
    const float* tzv  = (const float*)d_in[8];
    const float* tLv  = (const float*)d_in[9];
    const float* w1f  = (const float*)d_in[10];
    const float* w2f  = (const float*)d_in[11];
    const float* w1b  = (const float*)d_in[12];
    const float* w2b  = (const float*)d_in[13];

    float* Zout  = (float*)d_out;                       // [9][NBP]
    float* Sout  = Zout + (size_t)NLAYERS * NBP;        // [9][NBP]
    float* WLout = Zout + 2 * (size_t)NLAYERS * NBP;    // [327*327]

    char* ws = (char*)d_ws;
    size_t off = 0;
    auto alloc = [&](size_t bytes) -> void* {
        void* p = ws + off;
        off += (bytes + 255) & ~(size_t)255;
        return p;
    };

    float* w2fT = (float*)alloc(9216 * 4);
    float* w1bT = (float*)alloc(9216 * 4);
    float* P    = (float*)alloc((size_t)NDIM * NDIM * 4);
    float* PB   = (float*)alloc((size_t)NBP * 4);
    float* Xa   = (float*)alloc((size_t)NBP * 4);
    float* Xb_  = (float*)alloc((size_t)NBP * 4);
    float* La   = (float*)alloc((size_t)NBP * 4);
    float* Lb_  = (float*)alloc((size_t)NBP * 4);
    float* zfb  = (float*)alloc((size_t)NBP * 4);   // doubles as hatx temp

    size_t rem = (ws_size > off + 4096) ? (ws_size - off - 4096) : 0;
    long long Ci = (long long)(rem / (2 * 25600 * 4));
    if (Ci > 2048) Ci = 2048;
    if (Ci < 1) Ci = 1;
    int C = (int)Ci;
    float* Abuf = (float*)alloc((size_t)C * 25600 * 4);
    float* Bbuf = (float*)alloc((size_t)C * 25600 * 4);

    int ew_grid = (NBP + 255) / 256;

    k_wtrans<<<36, 256, 0, stream>>>(w2f, w2fT);
    k_wtrans<<<36, 256, 0, stream>>>(w1b, w1bT);
    k_phitphi<<<dim3(50, 50), dim3(16, 16), 0, stream>>>(Wf, P);
    k_wloss<<<(MDIM * MDIM + 255) / 256, 256, 0, stream>>>(Wf, WLout);
    k_phitb<<<ew_grid, 256, 0, stream>>>(y, Wf, PB);

    float* Xcur = Xa; float* Xoth = Xb_;
    float* Lcur = La; float* Loth = Lb_;

    for (int i = 0; i < NLAYERS; ++i) {
        int mode = (i == 0) ? 0 : ((i == 1) ? 1 : 2);
        float* Zw = Zout + (size_t)i * NBP;
        const float* Zc = Zout + (size_t)((i >= 1) ? (i - 1) : 0) * NBP;
        const float* Zp = Zout + (size_t)((i >= 2) ? (i - 2) : 0) * NBP;

        float* Xn;
        if (i == 0) {
            Xn = Xcur;
            k_x0<<<ew_grid, 256, 0, stream>>>(PB, Xn, hv);
        } else {
            k_hatx<<<ew_grid, 256, 0, stream>>>(Xcur, Xoth, zfb, txv, i, mode);
            Xn = Xoth;
            k_xmm<<<dim3(13, 64), 256, 0, stream>>>(zfb, P, PB, Lcur, Zc, Xn,
                                                    hv, b1v, i, mode);
            float* t = Xcur; Xcur = Xn; Xoth = t;
        }

        k_zflat<<<ew_grid, 256, 0, stream>>>(Xn, Zc, Zp, Lcur, zfb, hv, b2v, tzv, i, mode);

        for (int c0 = 0; c0 < NB; c0 += C) {
            int g = (NB - c0 < C) ? (NB - c0) : C;
            k_conv1f<<<g, 512, 0, stream>>>(zfb, Abuf, w1f, c0);
            k_conv32<<<g, 512, 0, stream>>>(Abuf, Bbuf, w2fT, stv, i, 0, 0);   // x_fwd
            k_conv32<<<g, 512, 0, stream>>>(Bbuf, Abuf, w1bT, stv, i, 1, 1);   // relu(c1b(soft(x_fwd)))
            k_conv2b<<<g, 512, 0, stream>>>(Abuf, w2b, zfb, Zw, 0, c0);        // Zs[i]
            k_conv32<<<g, 512, 0, stream>>>(Bbuf, Abuf, w1bT, stv, i, 0, 1);   // relu(c1b(x_fwd))
            k_conv2b<<<g, 512, 0, stream>>>(Abuf, w2b, zfb, Sout + (size_t)i * NBP, 1, c0); // syms[i]
        }

        k_lup<<<ew_grid, 256, 0, stream>>>(Xn, Zw, Lcur, Loth, Loth, hv, b1v, tLv, i, mode);
        { float* t = Lcur; Lcur = Loth; Loth = t; }
    }
}

// Round 2
// 25795.239 us; speedup vs baseline: 2.4805x; 1.2845x over previous
//
#include <hip/hip_runtime.h>
#include <hip/hip_bf16.h>

#define NB 4096
#define MDIM 327
#define NDIM 800
#define NLAYERS 9
#define NPIX 800
#define CHN 32
#define NBP (NB * NPIX)

typedef __hip_bfloat16 bf16;

// ---------------- setup ----------------

__global__ void k_copy(const float* __restrict__ src, float* __restrict__ dst,
                       long long n) {
    long long i0 = (long long)blockIdx.x * 256 + threadIdx.x;
    long long stride = (long long)gridDim.x * 256;
    for (long long i = i0; i < n; i += stride) dst[i] = src[i];
}

// transpose [O=32][I*9=288] -> [288][32]
__global__ void k_wtrans(const float* __restrict__ src, float* __restrict__ dst) {
    int idx = blockIdx.x * 256 + threadIdx.x;
    if (idx >= 9216) return;
    int o = idx / 288, r = idx % 288;
    dst[r * 32 + o] = src[idx];
}

__global__ void k_phitphi(const float* __restrict__ W, float* __restrict__ P) {
    int b = blockIdx.x * 16 + threadIdx.x;
    int a = blockIdx.y * 16 + threadIdx.y;
    float acc = 0.f;
    for (int k = 0; k < MDIM; ++k)
        acc += W[k * NDIM + a] * W[k * NDIM + b];
    P[(size_t)a * NDIM + b] = acc;
}

__global__ void k_wloss(const float* __restrict__ W, float* __restrict__ out) {
    int idx = blockIdx.x * 256 + threadIdx.x;
    if (idx >= MDIM * MDIM) return;
    int a = idx / MDIM, b = idx % MDIM;
    float acc = 0.f;
    for (int n = 0; n < NDIM; ++n)
        acc += W[a * NDIM + n] * W[b * NDIM + n];
    if (a == b) acc -= 1.f;
    out[idx] = acc;
}

__global__ void k_phitb(const float* __restrict__ y, const float* __restrict__ W,
                        float* __restrict__ PB) {
    int idx = blockIdx.x * 256 + threadIdx.x;
    if (idx >= NBP) return;
    int b = idx / NDIM, n = idx % NDIM;
    float acc = 0.f;
    for (int k = 0; k < MDIM; ++k)
        acc += y[b * MDIM + k] * W[k * NDIM + n];
    PB[idx] = acc;
}

// ---------------- X update ----------------

__global__ void k_x0(const float* __restrict__ PB, float* __restrict__ X1,
                     const float* __restrict__ hv) {
    int idx = blockIdx.x * 256 + threadIdx.x;
    if (idx >= NBP) return;
    X1[idx] = hv[0] * PB[idx];
}

// H = hatx = (1+tx)*Xc - tx*Xp
__global__ void k_hatx(const float* __restrict__ Xc, const float* __restrict__ Xp,
                       float* __restrict__ H, const float* __restrict__ txv,
                       int layer, int mode) {
    int idx = blockIdx.x * 256 + threadIdx.x;
    if (idx >= NBP) return;
    float tx = txv[layer];
    float xc = Xc[idx];
    float xp = (mode >= 2) ? Xp[idx] : 0.f;
    H[idx] = (1.f + tx) * xc - tx * xp;
}

// Xn = H*(1-h*b1) + h*PB - h*(H@P) + h*b1*Z - h*L
__global__ void k_xmm(const float* __restrict__ H, const float* __restrict__ P,
                      const float* __restrict__ PB, const float* __restrict__ Lc,
                      const float* __restrict__ Zc, float* __restrict__ Xn,
                      const float* __restrict__ hv, const float* __restrict__ b1v,
                      int layer, int mode) {
    __shared__ float As[64][17];
    __shared__ float Bs[16][65];
    int tid = threadIdx.x;
    float h = hv[layer], b1 = b1v[layer];
    int rowbase = blockIdx.y * 64, colbase = blockIdx.x * 64;
    int ttx = tid % 16, tty = tid / 16;
    float acc[4][4];
#pragma unroll
    for (int r = 0; r < 4; ++r)
#pragma unroll
        for (int c = 0; c < 4; ++c) acc[r][c] = 0.f;

    int am = tid >> 2, ak4 = (tid & 3) * 4;
    int bk = tid >> 4, bn4 = (tid & 15) * 4;

    for (int kt = 0; kt < 50; ++kt) {
        int k0 = kt * 16;
        {
            const float* hp = H + (size_t)(rowbase + am) * NDIM + k0 + ak4;
#pragma unroll
            for (int j = 0; j < 4; ++j) As[am][ak4 + j] = hp[j];
        }
        {
            const float* pr = P + (size_t)(k0 + bk) * NDIM + colbase + bn4;
#pragma unroll
            for (int j = 0; j < 4; ++j) {
                int col = colbase + bn4 + j;
                Bs[bk][bn4 + j] = (col < NDIM) ? pr[j] : 0.f;
            }
        }
        __syncthreads();
#pragma unroll
        for (int kk = 0; kk < 16; ++kk) {
            float a[4], b[4];
#pragma unroll
            for (int r = 0; r < 4; ++r) a[r] = As[tty * 4 + r][kk];
#pragma unroll
            for (int c = 0; c < 4; ++c) b[c] = Bs[kk][ttx * 4 + c];
#pragma unroll
            for (int r = 0; r < 4; ++r)
#pragma unroll
                for (int c = 0; c < 4; ++c) acc[r][c] += a[r] * b[c];
        }
        __syncthreads();
    }

#pragma unroll
    for (int r = 0; r < 4; ++r) {
        int row = rowbase + tty * 4 + r;
#pragma unroll
        for (int c = 0; c < 4; ++c) {
            int col = colbase + ttx * 4 + c;
            if (col >= NDIM) continue;
            size_t idx = (size_t)row * NDIM + col;
            float hx = H[idx];
            float zt = (mode == 2) ? Zc[idx] : 0.f;
            float lt = (mode == 2) ? Lc[idx] : 0.f;
            Xn[idx] = hx * (1.f - h * b1) + h * PB[idx] - h * acc[r][c] + h * b1 * zt - h * lt;
        }
    }
}

// ---------------- z_flat ----------------

__global__ void k_zflat(const float* __restrict__ Xn, const float* __restrict__ Zc,
                        const float* __restrict__ Zp, const float* __restrict__ Lc,
                        float* __restrict__ zf,
                        const float* __restrict__ hv, const float* __restrict__ b2v,
                        const float* __restrict__ tzv, int layer, int mode) {
    int idx = blockIdx.x * 256 + threadIdx.x;
    if (idx >= NBP) return;
    float h = hv[layer], b2 = b2v[layer], tz = tzv[layer];
    float hatz, lt;
    if (mode == 0) { hatz = 0.f; lt = 0.f; }
    else if (mode == 1) { hatz = (1.f + tz) * Zc[idx]; lt = 0.f; }
    else {
        float zc = Zc[idx], zp = Zp[idx];
        hatz = zc + tz * (zc - zp);
        lt = Lc[idx];
    }
    zf[idx] = hatz + h * (lt + b2 * (Xn[idx] - hatz));
}

// ---------------- convs (f32) ----------------
// conv32/conv2b v2: LDS row stride 44 words (16B-aligned rows), data at
// words 1..40 (pixel x -> word x+1), borders {0,41,42,43} zeroed by the
// staging threads themselves. Channels staged in 2 groups of 16
// (16*12*44*4 = 33792 B LDS -> 3 blocks/CU at launch_bounds(512,6)).
// Window reads are 3x ds_read_b128 per row (lane base (ry*44+8g) is
// 16B-aligned; base/4 mod 8 spreads <=7 lanes per 4-bank group = phase
// floor -> no bank conflicts). Lane map: lane<50, ry=lane/5,
// xg=(lane%5)*8; each lane: 4 och x 8 px (conv32) / 8 px (conv2b).
// Accumulation order per output stays ci(0..31) -> ky -> kx.

// 1->32 conv + relu. w: [32][1][3][3] raw.
__global__ void __launch_bounds__(512, 4)
k_conv1f(const float* __restrict__ zf, float* __restrict__ out,
         const float* __restrict__ w, int c0) {
    __shared__ float zs[22 * 42];
    int tid = threadIdx.x;
    int img = c0 + blockIdx.x;
    for (int i = tid; i < 22 * 42; i += 512) zs[i] = 0.f;
    __syncthreads();
    for (int p = tid; p < NPIX; p += 512) {
        int y = p / 40, x = p % 40;
        zs[(y + 1) * 42 + (x + 1)] = zf[(size_t)img * NPIX + p];
    }
    __syncthreads();

    int wv = __builtin_amdgcn_readfirstlane(tid >> 6);
    int ob = wv * 4;
    int lane = tid & 63;
    int ry = lane / 5;
    int xg = (lane % 5) * 8;
    bool active = lane < 50;

    float wreg[4][9];
#pragma unroll
    for (int oo = 0; oo < 4; ++oo)
#pragma unroll
        for (int q = 0; q < 9; ++q) wreg[oo][q] = w[(ob + oo) * 9 + q];

    if (active) {
#pragma unroll
        for (int half = 0; half < 2; ++half) {
            int orow = half * 10 + ry;
            float pv[3][10];
#pragma unroll
            for (int r = 0; r < 3; ++r)
#pragma unroll
                for (int j = 0; j < 10; ++j)
                    pv[r][j] = zs[(orow + r) * 42 + xg + j];
            float acc[4][8];
#pragma unroll
            for (int oo = 0; oo < 4; ++oo)
#pragma unroll
                for (int j = 0; j < 8; ++j) acc[oo][j] = 0.f;
#pragma unroll
            for (int ky = 0; ky < 3; ++ky)
#pragma unroll
                for (int kx = 0; kx < 3; ++kx) {
                    int q = ky * 3 + kx;
#pragma unroll
                    for (int j = 0; j < 8; ++j) {
                        float p = pv[ky][kx + j];
                        acc[0][j] += wreg[0][q] * p;
                        acc[1][j] += wreg[1][q] * p;
                        acc[2][j] += wreg[2][q] * p;
                        acc[3][j] += wreg[3][q] * p;
                    }
                }
#pragma unroll
            for (int oo = 0; oo < 4; ++oo) {
                float* op = out + (size_t)blockIdx.x * 25600 + (ob + oo) * 800
                            + orow * 40 + xg;
#pragma unroll
                for (int j = 0; j < 8; ++j) op[j] = fmaxf(acc[oo][j], 0.f);
            }
        }
    }
}

// 32->32 conv. wT: [ci*9+ky*3+kx][32 o]. Optional soft-threshold on input,
// relu on output.
__global__ void __launch_bounds__(512, 6)
k_conv32(const float* __restrict__ in, float* __restrict__ out,
         const float* __restrict__ wT, const float* __restrict__ thrv,
         int layer, int softflag, int reluflag) {
    __shared__ alignas(16) float inS[16 * 12 * 44];   // 33792 B
    int tid = threadIdx.x;
    const float* ip = in + (size_t)blockIdx.x * 25600;
    float thr = softflag ? fabsf(thrv[layer]) : 0.f;

    int wv = __builtin_amdgcn_readfirstlane(tid >> 6);
    int ob = wv * 4;
    int lane = tid & 63;
    int ry = lane / 5;
    int xg = (lane % 5) * 8;
    bool active = lane < 50;

    // staging role: threads 0..383, one half-row (20 px) each
    int sr = tid >> 1, sh = tid & 1;
    int sc = sr / 12, srr = sr - sc * 12;

    for (int half = 0; half < 2; ++half) {
        float acc[4][8];
#pragma unroll
        for (int oo = 0; oo < 4; ++oo)
#pragma unroll
            for (int j = 0; j < 8; ++j) acc[oo][j] = 0.f;

        for (int cg = 0; cg < 2; ++cg) {
            __syncthreads();   // prior compute done reading inS
            if (tid < 384) {
                float* drow = inS + sc * 528 + srr * 44;
                if (sh == 0) drow[0] = 0.f;
                else { drow[41] = 0.f; drow[42] = 0.f; drow[43] = 0.f; }
                int gr = half * 10 - 1 + srr;
                float* d = drow + 1 + sh * 20;
                if (gr >= 0 && gr < 20) {
                    const float4* src = reinterpret_cast<const float4*>(
                        ip + (size_t)(cg * 16 + sc) * 800 + gr * 40 + sh * 20);
                    float v[20];
#pragma unroll
                    for (int q4 = 0; q4 < 5; ++q4) {
                        float4 u = src[q4];
                        v[q4 * 4 + 0] = u.x; v[q4 * 4 + 1] = u.y;
                        v[q4 * 4 + 2] = u.z; v[q4 * 4 + 3] = u.w;
                    }
                    if (softflag) {
#pragma unroll
                        for (int j = 0; j < 20; ++j) {
                            float a = fabsf(v[j]) - thr;
                            v[j] = (a > 0.f) ? copysignf(a, v[j]) : 0.f;
                        }
                    }
#pragma unroll
                    for (int j = 0; j < 20; ++j) d[j] = v[j];
                } else {
#pragma unroll
                    for (int j = 0; j < 20; ++j) d[j] = 0.f;
                }
            }
            __syncthreads();   // staged data visible

            if (active) {
#pragma unroll 1
                for (int ci = 0; ci < 16; ++ci) {
                    const float* rs = inS + ci * 528 + ry * 44 + xg;
                    const float* wc = wT + (size_t)(cg * 16 + ci) * 288 + ob;
#pragma unroll
                    for (int ky = 0; ky < 3; ++ky) {
                        const float4* rp =
                            reinterpret_cast<const float4*>(rs + ky * 44);
                        float4 u = rp[0], v2 = rp[1], w2 = rp[2];
                        float p[12];
                        p[0] = u.x;  p[1] = u.y;  p[2] = u.z;  p[3] = u.w;
                        p[4] = v2.x; p[5] = v2.y; p[6] = v2.z; p[7] = v2.w;
                        p[8] = w2.x; p[9] = w2.y; p[10] = w2.z; p[11] = w2.w;
#pragma unroll
                        for (int kx = 0; kx < 3; ++kx) {
                            int q = ky * 3 + kx;
                            float w0 = wc[q * 32 + 0];
                            float w1 = wc[q * 32 + 1];
                            float w2_ = wc[q * 32 + 2];
                            float w3 = wc[q * 32 + 3];
#pragma unroll
                            for (int j = 0; j < 8; ++j) {
                                float pj = p[kx + j];
                                acc[0][j] += w0 * pj;
                                acc[1][j] += w1 * pj;
                                acc[2][j] += w2_ * pj;
                                acc[3][j] += w3 * pj;
                            }
                        }
                    }
                }
            }
        }

        if (active) {
            int orow = half * 10 + ry;
#pragma unroll
            for (int oo = 0; oo < 4; ++oo) {
                float* op = out + (size_t)blockIdx.x * 25600 + (ob + oo) * 800
                            + orow * 40 + xg;
#pragma unroll
                for (int j = 0; j < 8; ++j) {
                    float vv = acc[oo][j];
                    if (reluflag) vv = fmaxf(vv, 0.f);
                    op[j] = vv;
                }
            }
        }
    }
}

// 32->1 conv; writes f32 to global output; optional -z_in.
// 8 waves; wave wv owns local channels {2wv, 2wv+1} of each 16-ch group
// (4 global ci total); partial sums reduced through LDS (aliased on inS).
__global__ void __launch_bounds__(512, 6)
k_conv2b(const float* __restrict__ in, const float* __restrict__ w,
         const float* __restrict__ zf, float* __restrict__ out,
         int subz, int c0) {
    __shared__ alignas(16) float inS[16 * 12 * 44];   // 33792 B; head reused as psum
    float* psum = inS;
    int tid = threadIdx.x;
    int img = c0 + blockIdx.x;
    const float* ip = in + (size_t)blockIdx.x * 25600;

    int wv = __builtin_amdgcn_readfirstlane(tid >> 6);
    int lane = tid & 63;
    int ry = lane / 5;
    int xg = (lane % 5) * 8;
    bool active = lane < 50;

    int sr = tid >> 1, sh = tid & 1;
    int sc = sr / 12, srr = sr - sc * 12;

    for (int half = 0; half < 2; ++half) {
        float acc[8];
#pragma unroll
        for (int j = 0; j < 8; ++j) acc[j] = 0.f;

        for (int cg = 0; cg < 2; ++cg) {
            __syncthreads();   // prior reads of inS (compute or reduce) done
            if (tid < 384) {
                float* drow = inS + sc * 528 + srr * 44;
                if (sh == 0) drow[0] = 0.f;
                else { drow[41] = 0.f; drow[42] = 0.f; drow[43] = 0.f; }
                int gr = half * 10 - 1 + srr;
                float* d = drow + 1 + sh * 20;
                if (gr >= 0 && gr < 20) {
                    const float4* src = reinterpret_cast<const float4*>(
                        ip + (size_t)(cg * 16 + sc) * 800 + gr * 40 + sh * 20);
#pragma unroll
                    for (int q4 = 0; q4 < 5; ++q4) {
                        float4 u = src[q4];
                        d[q4 * 4 + 0] = u.x; d[q4 * 4 + 1] = u.y;
                        d[q4 * 4 + 2] = u.z; d[q4 * 4 + 3] = u.w;
                    }
                } else {
#pragma unroll
                    for (int j = 0; j < 20; ++j) d[j] = 0.f;
                }
            }
            __syncthreads();

            if (active) {
#pragma unroll
                for (int k = 0; k < 2; ++k) {
                    int cil = wv * 2 + k;   // 0..15
                    const float* rs = inS + cil * 528 + ry * 44 + xg;
                    const float* wc = w + (size_t)(cg * 16 + cil) * 9;
#pragma unroll
                    for (int ky = 0; ky < 3; ++ky) {
                        const float4* rp =
                            reinterpret_cast<const float4*>(rs + ky * 44);
                        float4 u = rp[0], v2 = rp[1], w2 = rp[2];
                        float p[12];
                        p[0] = u.x;  p[1] = u.y;  p[2] = u.z;  p[3] = u.w;
                        p[4] = v2.x; p[5] = v2.y; p[6] = v2.z; p[7] = v2.w;
                        p[8] = w2.x; p[9] = w2.y; p[10] = w2.z; p[11] = w2.w;
#pragma unroll
                        for (int kx = 0; kx < 3; ++kx) {
                            float wq = wc[ky * 3 + kx];
#pragma unroll
                            for (int j = 0; j < 8; ++j)
                                acc[j] += wq * p[kx + j];
                        }
                    }
                }
            }
        }

        __syncthreads();   // all compute reads of inS done -> reuse as psum
        if (active) {
#pragma unroll
            for (int j = 0; j < 8; ++j)
                psum[wv * 400 + ry * 40 + xg + j] = acc[j];
        }
        __syncthreads();
        for (int p = tid; p < 400; p += 512) {
            float s = 0.f;
#pragma unroll
            for (int u = 0; u < 8; ++u) s += psum[u * 400 + p];
            size_t gidx = (size_t)img * NPIX + half * 400 + p;
            if (subz) s -= zf[gidx];
            out[gidx] = s;
        }
    }
}

// ---------------- L update ----------------

__global__ void k_lup(const float* __restrict__ Xn, const float* __restrict__ Zn,
                      const float* __restrict__ Lc, const float* __restrict__ Lp,
                      float* __restrict__ Ln,
                      const float* __restrict__ hv, const float* __restrict__ b1v,
                      const float* __restrict__ tLv, int layer, int mode) {
    int idx = blockIdx.x * 256 + threadIdx.x;
    if (idx >= NBP) return;
    float h = hv[layer], b1 = b1v[layer], tL = tLv[layer];
    float hatL;
    if (mode == 0) hatL = 0.f;
    else if (mode == 1) hatL = (1.f + tL) * Lc[idx];
    else {
        float lc = Lc[idx], lp = Lp[idx];
        hatL = lc + tL * (lc - lp);
    }
    Ln[idx] = hatL + h * b1 * (Xn[idx] - Zn[idx]);
}

// ---------------- host ----------------
// PROBE-VERIFIED (round 5): inputs f32, dict order, n_in=14, output f32, ws>=120MB.

extern "C" void kernel_launch(void* const* d_in, const int* in_sizes, int n_in,
                              void* d_out, int out_size, void* d_ws, size_t ws_size,
                              hipStream_t stream) {
    const float* y    = (const float*)d_in[0];
    const float* Wf   = (const float*)d_in[2];
    const float* b1v  = (const float*)d_in[3];
    const float* b2v  = (const float*)d_in[4];
    const float* hv   = (const float*)d_in[5];
    const float* stv  = (const float*)d_in[6];
    const float* txv  = (const float*)d_in[7];
    const float* tzv  = (const float*)d_in[8];
    const float* tLv  = (const float*)d_in[9];
    const float* w1f  = (const float*)d_in[10];
    const float* w2f  = (const float*)d_in[11];
    const float* w1b  = (const float*)d_in[12];
    const float* w2b  = (const float*)d_in[13];

    float* Zout  = (float*)d_out;                       // [9][NBP]
    float* Sout  = Zout + (size_t)NLAYERS * NBP;        // [9][NBP]
    float* WLout = Zout + 2 * (size_t)NLAYERS * NBP;    // [327*327]

    char* ws = (char*)d_ws;
    size_t off = 0;
    auto alloc = [&](size_t bytes) -> void* {
        void* p = ws + off;
        off += (bytes + 255) & ~(size_t)255;
        return p;
    };

    float* w2fT = (float*)alloc(9216 * 4);
    float* w1bT = (float*)alloc(9216 * 4);
    float* P    = (float*)alloc((size_t)NDIM * NDIM * 4);
    float* PB   = (float*)alloc((size_t)NBP * 4);
    float* Xa   = (float*)alloc((size_t)NBP * 4);
    float* Xb_  = (float*)alloc((size_t)NBP * 4);
    float* La   = (float*)alloc((size_t)NBP * 4);
    float* Lb_  = (float*)alloc((size_t)NBP * 4);
    float* zfb  = (float*)alloc((size_t)NBP * 4);   // doubles as hatx temp

    size_t rem = (ws_size > off + 4096) ? (ws_size - off - 4096) : 0;
    long long Ci = (long long)(rem / (2 * 25600 * 4));
    if (Ci > 2048) Ci = 2048;
    if (Ci < 1) Ci = 1;
    int C = (int)Ci;
    float* Abuf = (float*)alloc((size_t)C * 25600 * 4);
    float* Bbuf = (float*)alloc((size_t)C * 25600 * 4);

    int ew_grid = (NBP + 255) / 256;

    k_wtrans<<<36, 256, 0, stream>>>(w2f, w2fT);
    k_wtrans<<<36, 256, 0, stream>>>(w1b, w1bT);
    k_phitphi<<<dim3(50, 50), dim3(16, 16), 0, stream>>>(Wf, P);
    k_wloss<<<(MDIM * MDIM + 255) / 256, 256, 0, stream>>>(Wf, WLout);
    k_phitb<<<ew_grid, 256, 0, stream>>>(y, Wf, PB);

    float* Xcur = Xa; float* Xoth = Xb_;
    float* Lcur = La; float* Loth = Lb_;

    for (int i = 0; i < NLAYERS; ++i) {
        int mode = (i == 0) ? 0 : ((i == 1) ? 1 : 2);
        float* Zw = Zout + (size_t)i * NBP;
        const float* Zc = Zout + (size_t)((i >= 1) ? (i - 1) : 0) * NBP;
        const float* Zp = Zout + (size_t)((i >= 2) ? (i - 2) : 0) * NBP;

        float* Xn;
        if (i == 0) {
            Xn = Xcur;
            k_x0<<<ew_grid, 256, 0, stream>>>(PB, Xn, hv);
        } else {
            k_hatx<<<ew_grid, 256, 0, stream>>>(Xcur, Xoth, zfb, txv, i, mode);
            Xn = Xoth;
            k_xmm<<<dim3(13, 64), 256, 0, stream>>>(zfb, P, PB, Lcur, Zc, Xn,
                                                    hv, b1v, i, mode);
            float* t = Xcur; Xcur = Xn; Xoth = t;
        }

        k_zflat<<<ew_grid, 256, 0, stream>>>(Xn, Zc, Zp, Lcur, zfb, hv, b2v, tzv, i, mode);

        for (int c0 = 0; c0 < NB; c0 += C) {
            int g = (NB - c0 < C) ? (NB - c0) : C;
            k_conv1f<<<g, 512, 0, stream>>>(zfb, Abuf, w1f, c0);
            k_conv32<<<g, 512, 0, stream>>>(Abuf, Bbuf, w2fT, stv, i, 0, 0);   // x_fwd
            k_conv32<<<g, 512, 0, stream>>>(Bbuf, Abuf, w1bT, stv, i, 1, 1);   // relu(c1b(soft(x_fwd)))
            k_conv2b<<<g, 512, 0, stream>>>(Abuf, w2b, zfb, Zw, 0, c0);        // Zs[i]
            k_conv32<<<g, 512, 0, stream>>>(Bbuf, Abuf, w1bT, stv, i, 0, 1);   // relu(c1b(x_fwd))
            k_conv2b<<<g, 512, 0, stream>>>(Abuf, w2b, zfb, Sout + (size_t)i * NBP, 1, c0); // syms[i]
        }

        k_lup<<<ew_grid, 256, 0, stream>>>(Xn, Zw, Lcur, Loth, Loth, hv, b1v, tLv, i, mode);
        { float* t = Lcur; Lcur = Loth; Loth = t; }
    }
}